// Round 5
// baseline (182.456 us; speedup 1.0000x reference)
//
#include <hip/hip_runtime.h>
#include <stddef.h>

namespace {
constexpr int Hc = 256, Wc = 256, Cc = 64, Bc = 4, Dc = 81;
constexpr int CH = Hc * Wc;  // channel stride in floats
}

// guaranteed-zero 16B region for out-of-range horizontal window loads
__device__ __attribute__((aligned(16))) float g_zero4[4] = {0.f, 0.f, 0.f, 0.f};

// 36 FMAs into ACC: pixel w=4t+s, offset j=jj-4 -> window idx s-jj+8
#define FMAS(ACC, P, A, Bv, Cv)                                             \
    do {                                                                    \
        const float w_[12] = {A.x,  A.y,  A.z,  A.w,  Bv.x, Bv.y,           \
                              Bv.z, Bv.w, Cv.x, Cv.y, Cv.z, Cv.w};          \
        const float pv_[4] = {P.x, P.y, P.z, P.w};                          \
        _Pragma("unroll") for (int jj = 0; jj < 9; ++jj)                    \
            _Pragma("unroll") for (int s = 0; s < 4; ++s)                   \
                ACC[jj][s] += pv_[s] * w_[s - jj + 8];                      \
    } while (0)

// stage S: load x2 window (3 quads) + x1 rows h0,h1 quads; advance pointers
#define LOADSET(S)                                                          \
    do {                                                                    \
        wa##S = *reinterpret_cast<const float4*>(pA);                       \
        wb##S = *reinterpret_cast<const float4*>(pB);                       \
        wc##S = *reinterpret_cast<const float4*>(pC);                       \
        p##S  = *reinterpret_cast<const float4*>(x1a);                      \
        q##S  = *reinterpret_cast<const float4*>(x1b);                      \
        pA += dA; pB += CH; pC += dC; x1a += CH; x1b += CH;                 \
    } while (0)

// both rows' FMAs against the shared window of stage S (72 FMAs)
#define FMA2(S)                                                             \
    do {                                                                    \
        FMAS(accA, p##S, wa##S, wb##S, wc##S);                              \
        FMAS(accB, q##S, wa##S, wb##S, wc##S);                              \
    } while (0)

// Block = 10 waves (640 thr) = output rows {h0, h0+1}. Wave k owns x2 row
// r = h0-4+k and computes offset i=4-k for row h0 (k<=8) and i'=5-k for row
// h1 (k>=1) -- SAME x2 window serves both rows: 5 loads per 72 FMAs.
// Lane t owns pixels w=4t..4t+3. Depth-3 register pipeline.
// NOTE: no min-occupancy launch_bounds arg — (640,3) made the backend cap
// VGPR at 84 and spill ~70 regs to scratch (R4: WRITE_SIZE 97->167MB).
// Live set ~156 VGPR < 170 (= 512/3, the cap for a 10-wave block) so the
// block remains launchable.
__global__ __launch_bounds__(640)
void corr_softmax_kernel(const float* __restrict__ x1,
                         const float* __restrict__ x2,
                         float* __restrict__ out)
{
    __shared__ float redA[10][Wc];  // row h0 softmax reduction
    __shared__ float redB[10][Wc];  // row h1

    const int tid = threadIdx.x;
    const int k   = tid >> 6;   // 0..9
    const int t   = tid & 63;
    // XCD-aware swizzle (512 blocks, 64 consecutive row-pairs per XCD)
    const int bid = blockIdx.x;
    const int bh  = (bid & 7) * 64 + (bid >> 3);  // 0..511
    const int b   = bh >> 7;
    const int h0  = (bh & 127) * 2;
    const int h1  = h0 + 1;

    float accA[9][4], accB[9][4];
#pragma unroll
    for (int jj = 0; jj < 9; ++jj)
#pragma unroll
        for (int s = 0; s < 4; ++s) { accA[jj][s] = 0.f; accB[jj][s] = 0.f; }

    const int r = h0 - 4 + k;   // this wave's x2 row
    if ((unsigned)r < (unsigned)Hc) {
        const float* x1a = x1 + (size_t)b * Cc * CH + (size_t)h0 * Wc + 4 * t;
        const float* x1b = x1a + Wc;
        const float* xr  = x2 + (size_t)b * Cc * CH + (size_t)r * Wc + 4 * t;
        const float* pA = (t == 0)  ? g_zero4 : (xr - 4);
        const float* pB = xr;
        const float* pC = (t == 63) ? g_zero4 : (xr + 4);
        const ptrdiff_t dA = (t == 0)  ? 0 : CH;
        const ptrdiff_t dC = (t == 63) ? 0 : CH;

        float4 wa0, wb0, wc0, p0, q0;
        float4 wa1, wb1, wc1, p1, q1;
        float4 wa2, wb2, wc2, p2, q2;
        LOADSET(0);                        // ch 0
        LOADSET(1);                        // ch 1
#pragma unroll 1
        for (int it = 0; it < 20; ++it) {  // channels 3it .. 3it+2
            LOADSET(2); FMA2(0);
            LOADSET(0); FMA2(1);
            LOADSET(1); FMA2(2);
        }
        // loaded 0..61, computed 0..59
        LOADSET(2);  // ch 62
        FMA2(0);     // ch 60
        LOADSET(0);  // ch 63
        FMA2(1);     // ch 61
        FMA2(2);     // ch 62
        FMA2(0);     // ch 63
    }

    const bool vA = (k <= 8);  // row h0 channel i=4-k exists
    const bool vB = (k >= 1);  // row h1 channel i'=5-k exists
    const float NEG = -__builtin_inff();

    // ---- per-wave maxes ----
    float mA[4], mB[4];
#pragma unroll
    for (int s = 0; s < 4; ++s) { mA[s] = accA[0][s]; mB[s] = accB[0][s]; }
#pragma unroll
    for (int jj = 1; jj < 9; ++jj)
#pragma unroll
        for (int s = 0; s < 4; ++s) {
            mA[s] = fmaxf(mA[s], accA[jj][s]);
            mB[s] = fmaxf(mB[s], accB[jj][s]);
        }
    {
        float4 a = vA ? make_float4(mA[0], mA[1], mA[2], mA[3])
                      : make_float4(NEG, NEG, NEG, NEG);
        float4 bq = vB ? make_float4(mB[0], mB[1], mB[2], mB[3])
                       : make_float4(NEG, NEG, NEG, NEG);
        *reinterpret_cast<float4*>(&redA[k][4 * t]) = a;
        *reinterpret_cast<float4*>(&redB[k][4 * t]) = bq;
    }
    __syncthreads();

    float MA[4], MB[4];
    {
        float4 a = *reinterpret_cast<const float4*>(&redA[0][4 * t]);
        float4 bq = *reinterpret_cast<const float4*>(&redB[0][4 * t]);
        MA[0] = a.x; MA[1] = a.y; MA[2] = a.z; MA[3] = a.w;
        MB[0] = bq.x; MB[1] = bq.y; MB[2] = bq.z; MB[3] = bq.w;
#pragma unroll
        for (int w2 = 1; w2 < 10; ++w2) {
            float4 aa = *reinterpret_cast<const float4*>(&redA[w2][4 * t]);
            float4 bb = *reinterpret_cast<const float4*>(&redB[w2][4 * t]);
            MA[0] = fmaxf(MA[0], aa.x); MA[1] = fmaxf(MA[1], aa.y);
            MA[2] = fmaxf(MA[2], aa.z); MA[3] = fmaxf(MA[3], aa.w);
            MB[0] = fmaxf(MB[0], bb.x); MB[1] = fmaxf(MB[1], bb.y);
            MB[2] = fmaxf(MB[2], bb.z); MB[3] = fmaxf(MB[3], bb.w);
        }
    }

    // ---- exp + per-wave partial sums ----
    float sA[4] = {0.f, 0.f, 0.f, 0.f}, sB[4] = {0.f, 0.f, 0.f, 0.f};
#pragma unroll
    for (int jj = 0; jj < 9; ++jj)
#pragma unroll
        for (int s = 0; s < 4; ++s) {
            accA[jj][s] = __expf(accA[jj][s] - MA[s]); sA[s] += accA[jj][s];
            accB[jj][s] = __expf(accB[jj][s] - MB[s]); sB[s] += accB[jj][s];
        }
    __syncthreads();  // all maxes consumed
    {
        float4 a = vA ? make_float4(sA[0], sA[1], sA[2], sA[3])
                      : make_float4(0.f, 0.f, 0.f, 0.f);
        float4 bq = vB ? make_float4(sB[0], sB[1], sB[2], sB[3])
                       : make_float4(0.f, 0.f, 0.f, 0.f);
        *reinterpret_cast<float4*>(&redA[k][4 * t]) = a;
        *reinterpret_cast<float4*>(&redB[k][4 * t]) = bq;
    }
    __syncthreads();

    float SA[4], SB[4];
    {
        float4 a = *reinterpret_cast<const float4*>(&redA[0][4 * t]);
        float4 bq = *reinterpret_cast<const float4*>(&redB[0][4 * t]);
        SA[0] = a.x; SA[1] = a.y; SA[2] = a.z; SA[3] = a.w;
        SB[0] = bq.x; SB[1] = bq.y; SB[2] = bq.z; SB[3] = bq.w;
#pragma unroll
        for (int w2 = 1; w2 < 10; ++w2) {
            float4 aa = *reinterpret_cast<const float4*>(&redA[w2][4 * t]);
            float4 bb = *reinterpret_cast<const float4*>(&redB[w2][4 * t]);
            SA[0] += aa.x; SA[1] += aa.y; SA[2] += aa.z; SA[3] += aa.w;
            SB[0] += bb.x; SB[1] += bb.y; SB[2] += bb.z; SB[3] += bb.w;
        }
    }

    // ---- writes: kch = (9*i + j) mod 81 ----
    float* ob = out + (size_t)b * Dc * CH + 4 * t;
    if (vA) {
        const float i0 = 1.f/SA[0], i1 = 1.f/SA[1], i2 = 1.f/SA[2], i3 = 1.f/SA[3];
        int base = 32 - 9 * k;            // (9*(4-k) - 4) mod 81, jj=0
        base = (base % 81 + 81) % 81;
#pragma unroll
        for (int jj = 0; jj < 9; ++jj) {
            int kc = base + jj; if (kc >= 81) kc -= 81;
            float4 o = make_float4(accA[jj][0]*i0, accA[jj][1]*i1,
                                   accA[jj][2]*i2, accA[jj][3]*i3);
            *reinterpret_cast<float4*>(ob + (size_t)kc * CH + (size_t)h0 * Wc) = o;
        }
    }
    if (vB) {
        const float i0 = 1.f/SB[0], i1 = 1.f/SB[1], i2 = 1.f/SB[2], i3 = 1.f/SB[3];
        int base = 41 - 9 * k;            // (9*(5-k) - 4) mod 81, jj=0
        base = (base % 81 + 81) % 81;
#pragma unroll
        for (int jj = 0; jj < 9; ++jj) {
            int kc = base + jj; if (kc >= 81) kc -= 81;
            float4 o = make_float4(accB[jj][0]*i0, accB[jj][1]*i1,
                                   accB[jj][2]*i2, accB[jj][3]*i3);
            *reinterpret_cast<float4*>(ob + (size_t)kc * CH + (size_t)h1 * Wc) = o;
        }
    }
}

extern "C" void kernel_launch(void* const* d_in, const int* in_sizes, int n_in,
                              void* d_out, int out_size, void* d_ws, size_t ws_size,
                              hipStream_t stream) {
    (void)in_sizes; (void)n_in; (void)d_ws; (void)ws_size; (void)out_size;
    const float* x1 = (const float*)d_in[0];
    const float* x2 = (const float*)d_in[1];
    float* out = (float*)d_out;
    dim3 grid(Bc * Hc / 2);  // 512 blocks: one per (b, row-pair)
    dim3 block(640);         // 10 waves
    hipLaunchKernelGGL(corr_softmax_kernel, grid, block, 0, stream, x1, x2, out);
}

// Round 6
// 124.663 us; speedup vs baseline: 1.4636x; 1.4636x over previous
//
#include <hip/hip_runtime.h>
#include <stddef.h>

namespace {
constexpr int Hc = 256, Wc = 256, Cc = 64, Bc = 4, Dc = 81;
constexpr int CH = Hc * Wc;  // channel stride in floats
}

// guaranteed-zero 16B region for out-of-range horizontal window loads
__device__ __attribute__((aligned(16))) float g_zero4[4] = {0.f, 0.f, 0.f, 0.f};

// 36 FMAs into ACC: pixel w=4t+s, offset j=jj-4 -> window idx s-jj+8
#define FMAS(ACC, P, A, Bv, Cv)                                             \
    do {                                                                    \
        const float w_[12] = {A.x,  A.y,  A.z,  A.w,  Bv.x, Bv.y,           \
                              Bv.z, Bv.w, Cv.x, Cv.y, Cv.z, Cv.w};          \
        const float pv_[4] = {P.x, P.y, P.z, P.w};                          \
        _Pragma("unroll") for (int jj = 0; jj < 9; ++jj)                    \
            _Pragma("unroll") for (int s = 0; s < 4; ++s)                   \
                ACC[jj][s] += pv_[s] * w_[s - jj + 8];                      \
    } while (0)

// stage S: load x2 window (3 quads) + x1 rows h0,h1 quads; advance pointers
#define LOADSET(S)                                                          \
    do {                                                                    \
        wa##S = *reinterpret_cast<const float4*>(pA);                       \
        wb##S = *reinterpret_cast<const float4*>(pB);                       \
        wc##S = *reinterpret_cast<const float4*>(pC);                       \
        p##S  = *reinterpret_cast<const float4*>(x1a);                      \
        q##S  = *reinterpret_cast<const float4*>(x1b);                      \
        pA += dA; pB += CH; pC += dC; x1a += CH; x1b += CH;                 \
    } while (0)

// pin: loads issued before this point may not sink below it (FMAs are
// register-only and still schedule freely)
#define PIN() asm volatile("" ::: "memory")

// both rows' FMAs against the shared window of stage S (72 FMAs)
#define FMA2(S)                                                             \
    do {                                                                    \
        FMAS(accA, p##S, wa##S, wb##S, wc##S);                              \
        FMAS(accB, q##S, wa##S, wb##S, wc##S);                              \
    } while (0)

// Block = 10 waves (640 thr) = output rows {h0, h0+1}. Wave k owns x2 row
// r = h0-4+k and computes offset i=4-k for row h0 (k<=8) and i'=5-k for row
// h1 (k>=1) -- SAME x2 window serves both rows: 5 loads per 72 FMAs.
// Lane t owns pixels w=4t..4t+3. Depth-3 register pipeline.
// amdgpu_waves_per_eu(1,3): caps the GCN scheduler's occupancy TARGET at
// 3 waves/EU -> ~168 VGPR budget. Without it the scheduler targets ~6/EU
// (85 VGPR) and spills ~66 regs/thread (R4/R5: WRITE_SIZE 97->167MB,
// VALUBusy 16%). Live set ~150 VGPR fits 168 with no spill.
__global__ __launch_bounds__(640)
__attribute__((amdgpu_waves_per_eu(1, 3)))
void corr_softmax_kernel(const float* __restrict__ x1,
                         const float* __restrict__ x2,
                         float* __restrict__ out)
{
    __shared__ float redA[10][Wc];  // row h0 softmax reduction
    __shared__ float redB[10][Wc];  // row h1

    const int tid = threadIdx.x;
    const int k   = tid >> 6;   // 0..9
    const int t   = tid & 63;
    // XCD-aware swizzle (512 blocks, 64 consecutive row-pairs per XCD)
    const int bid = blockIdx.x;
    const int bh  = (bid & 7) * 64 + (bid >> 3);  // 0..511
    const int b   = bh >> 7;
    const int h0  = (bh & 127) * 2;
    const int h1  = h0 + 1;

    float accA[9][4], accB[9][4];
#pragma unroll
    for (int jj = 0; jj < 9; ++jj)
#pragma unroll
        for (int s = 0; s < 4; ++s) { accA[jj][s] = 0.f; accB[jj][s] = 0.f; }

    const int r = h0 - 4 + k;   // this wave's x2 row
    if ((unsigned)r < (unsigned)Hc) {
        const float* x1a = x1 + (size_t)b * Cc * CH + (size_t)h0 * Wc + 4 * t;
        const float* x1b = x1a + Wc;
        const float* xr  = x2 + (size_t)b * Cc * CH + (size_t)r * Wc + 4 * t;
        const float* pA = (t == 0)  ? g_zero4 : (xr - 4);
        const float* pB = xr;
        const float* pC = (t == 63) ? g_zero4 : (xr + 4);
        const ptrdiff_t dA = (t == 0)  ? 0 : CH;
        const ptrdiff_t dC = (t == 63) ? 0 : CH;

        float4 wa0, wb0, wc0, p0, q0;
        float4 wa1, wb1, wc1, p1, q1;
        float4 wa2, wb2, wc2, p2, q2;
        LOADSET(0);                        // ch 0
        PIN();
        LOADSET(1);                        // ch 1
        PIN();
#pragma unroll 1
        for (int it = 0; it < 20; ++it) {  // channels 3it .. 3it+2
            LOADSET(2); PIN(); FMA2(0);
            LOADSET(0); PIN(); FMA2(1);
            LOADSET(1); PIN(); FMA2(2);
        }
        // loaded 0..61, computed 0..59
        LOADSET(2);  // ch 62
        PIN();
        FMA2(0);     // ch 60
        LOADSET(0);  // ch 63
        PIN();
        FMA2(1);     // ch 61
        FMA2(2);     // ch 62
        FMA2(0);     // ch 63
    }

    const bool vA = (k <= 8);  // row h0 channel i=4-k exists
    const bool vB = (k >= 1);  // row h1 channel i'=5-k exists
    const float NEG = -__builtin_inff();

    // ---- per-wave maxes ----
    float mA[4], mB[4];
#pragma unroll
    for (int s = 0; s < 4; ++s) { mA[s] = accA[0][s]; mB[s] = accB[0][s]; }
#pragma unroll
    for (int jj = 1; jj < 9; ++jj)
#pragma unroll
        for (int s = 0; s < 4; ++s) {
            mA[s] = fmaxf(mA[s], accA[jj][s]);
            mB[s] = fmaxf(mB[s], accB[jj][s]);
        }
    {
        float4 a = vA ? make_float4(mA[0], mA[1], mA[2], mA[3])
                      : make_float4(NEG, NEG, NEG, NEG);
        float4 bq = vB ? make_float4(mB[0], mB[1], mB[2], mB[3])
                       : make_float4(NEG, NEG, NEG, NEG);
        *reinterpret_cast<float4*>(&redA[k][4 * t]) = a;
        *reinterpret_cast<float4*>(&redB[k][4 * t]) = bq;
    }
    __syncthreads();

    float MA[4], MB[4];
    {
        float4 a = *reinterpret_cast<const float4*>(&redA[0][4 * t]);
        float4 bq = *reinterpret_cast<const float4*>(&redB[0][4 * t]);
        MA[0] = a.x; MA[1] = a.y; MA[2] = a.z; MA[3] = a.w;
        MB[0] = bq.x; MB[1] = bq.y; MB[2] = bq.z; MB[3] = bq.w;
#pragma unroll
        for (int w2 = 1; w2 < 10; ++w2) {
            float4 aa = *reinterpret_cast<const float4*>(&redA[w2][4 * t]);
            float4 bb = *reinterpret_cast<const float4*>(&redB[w2][4 * t]);
            MA[0] = fmaxf(MA[0], aa.x); MA[1] = fmaxf(MA[1], aa.y);
            MA[2] = fmaxf(MA[2], aa.z); MA[3] = fmaxf(MA[3], aa.w);
            MB[0] = fmaxf(MB[0], bb.x); MB[1] = fmaxf(MB[1], bb.y);
            MB[2] = fmaxf(MB[2], bb.z); MB[3] = fmaxf(MB[3], bb.w);
        }
    }

    // ---- exp + per-wave partial sums ----
    float sA[4] = {0.f, 0.f, 0.f, 0.f}, sB[4] = {0.f, 0.f, 0.f, 0.f};
#pragma unroll
    for (int jj = 0; jj < 9; ++jj)
#pragma unroll
        for (int s = 0; s < 4; ++s) {
            accA[jj][s] = __expf(accA[jj][s] - MA[s]); sA[s] += accA[jj][s];
            accB[jj][s] = __expf(accB[jj][s] - MB[s]); sB[s] += accB[jj][s];
        }
    __syncthreads();  // all maxes consumed
    {
        float4 a = vA ? make_float4(sA[0], sA[1], sA[2], sA[3])
                      : make_float4(0.f, 0.f, 0.f, 0.f);
        float4 bq = vB ? make_float4(sB[0], sB[1], sB[2], sB[3])
                       : make_float4(0.f, 0.f, 0.f, 0.f);
        *reinterpret_cast<float4*>(&redA[k][4 * t]) = a;
        *reinterpret_cast<float4*>(&redB[k][4 * t]) = bq;
    }
    __syncthreads();

    float SA[4], SB[4];
    {
        float4 a = *reinterpret_cast<const float4*>(&redA[0][4 * t]);
        float4 bq = *reinterpret_cast<const float4*>(&redB[0][4 * t]);
        SA[0] = a.x; SA[1] = a.y; SA[2] = a.z; SA[3] = a.w;
        SB[0] = bq.x; SB[1] = bq.y; SB[2] = bq.z; SB[3] = bq.w;
#pragma unroll
        for (int w2 = 1; w2 < 10; ++w2) {
            float4 aa = *reinterpret_cast<const float4*>(&redA[w2][4 * t]);
            float4 bb = *reinterpret_cast<const float4*>(&redB[w2][4 * t]);
            SA[0] += aa.x; SA[1] += aa.y; SA[2] += aa.z; SA[3] += aa.w;
            SB[0] += bb.x; SB[1] += bb.y; SB[2] += bb.z; SB[3] += bb.w;
        }
    }

    // ---- writes: kch = (9*i + j) mod 81 ----
    float* ob = out + (size_t)b * Dc * CH + 4 * t;
    if (vA) {
        const float i0 = 1.f/SA[0], i1 = 1.f/SA[1], i2 = 1.f/SA[2], i3 = 1.f/SA[3];
        int base = 32 - 9 * k;            // (9*(4-k) - 4) mod 81, jj=0
        base = (base % 81 + 81) % 81;
#pragma unroll
        for (int jj = 0; jj < 9; ++jj) {
            int kc = base + jj; if (kc >= 81) kc -= 81;
            float4 o = make_float4(accA[jj][0]*i0, accA[jj][1]*i1,
                                   accA[jj][2]*i2, accA[jj][3]*i3);
            *reinterpret_cast<float4*>(ob + (size_t)kc * CH + (size_t)h0 * Wc) = o;
        }
    }
    if (vB) {
        const float i0 = 1.f/SB[0], i1 = 1.f/SB[1], i2 = 1.f/SB[2], i3 = 1.f/SB[3];
        int base = 41 - 9 * k;            // (9*(5-k) - 4) mod 81, jj=0
        base = (base % 81 + 81) % 81;
#pragma unroll
        for (int jj = 0; jj < 9; ++jj) {
            int kc = base + jj; if (kc >= 81) kc -= 81;
            float4 o = make_float4(accB[jj][0]*i0, accB[jj][1]*i1,
                                   accB[jj][2]*i2, accB[jj][3]*i3);
            *reinterpret_cast<float4*>(ob + (size_t)kc * CH + (size_t)h1 * Wc) = o;
        }
    }
}

extern "C" void kernel_launch(void* const* d_in, const int* in_sizes, int n_in,
                              void* d_out, int out_size, void* d_ws, size_t ws_size,
                              hipStream_t stream) {
    (void)in_sizes; (void)n_in; (void)d_ws; (void)ws_size; (void)out_size;
    const float* x1 = (const float*)d_in[0];
    const float* x2 = (const float*)d_in[1];
    float* out = (float*)d_out;
    dim3 grid(Bc * Hc / 2);  // 512 blocks: one per (b, row-pair)
    dim3 block(640);         // 10 waves
    hipLaunchKernelGGL(corr_softmax_kernel, grid, block, 0, stream, x1, x2, out);
}

// Round 7
// 88.549 us; speedup vs baseline: 2.0605x; 1.4078x over previous
//
#include <hip/hip_runtime.h>
#include <stddef.h>

namespace {
constexpr int Hc = 256, Wc = 256, Cc = 64, Bc = 4, Dc = 81;
constexpr int CH = Hc * Wc;  // channel stride in floats
}

// async global->LDS DMA: per-lane global src, wave-uniform LDS dest + lane*16
#define GLOAD_LDS16(g, l)                                                   \
    __builtin_amdgcn_global_load_lds(                                       \
        (const __attribute__((address_space(1))) void*)(g),                 \
        (__attribute__((address_space(3))) void*)(l), 16, 0, 0)

#define PIN() asm volatile("" ::: "memory")

// 36 FMAs: pixel w=4t+s, offset j=jj-4 -> padded window idx s-jj+8
#define FMAS(P, A, Bv, Cv)                                                  \
    do {                                                                    \
        const float w_[12] = {A.x,  A.y,  A.z,  A.w,  Bv.x, Bv.y,           \
                              Bv.z, Bv.w, Cv.x, Cv.y, Cv.z, Cv.w};          \
        const float pv_[4] = {P.x, P.y, P.z, P.w};                          \
        _Pragma("unroll") for (int jj = 0; jj < 9; ++jj)                    \
            _Pragma("unroll") for (int s = 0; s < 4; ++s)                   \
                acc[jj][s] += pv_[s] * w_[s - jj + 8];                      \
    } while (0)

// Steady-state phase for channel (base+Q), Q in 0..3, buffer Q, x1 slot pQ.
// Waits pair (DMA,x1) issued 4 channels ago; reads 3 window quads from the
// private LDS ring; drains DS; FMAs; re-issues the pair for channel +4 into
// the same buffer/slot. vmcnt(6): 8 outstanding ops, clear the oldest pair.
#define PHASE(Q)                                                            \
    do {                                                                    \
        asm volatile("s_waitcnt vmcnt(6)" ::: "memory");                    \
        float4 wa = *(const float4*)&xbuf[wi][Q][4 * t];                    \
        float4 wb = *(const float4*)&xbuf[wi][Q][4 * t + 4];                \
        float4 wc = *(const float4*)&xbuf[wi][Q][4 * t + 8];                \
        asm volatile("s_waitcnt lgkmcnt(0)" ::: "memory");                  \
        FMAS(p##Q, wa, wb, wc);                                             \
        GLOAD_LDS16(x2p + (size_t)(4 + Q) * CH, &xbuf[wi][Q][4]);           \
        p##Q = *(const float4*)(x1p + (size_t)(4 + Q) * CH);                \
        PIN();                                                              \
    } while (0)

// Tail phase: no re-issue, decreasing vmcnt drain.
#define PHASE_T(Q, N)                                                       \
    do {                                                                    \
        asm volatile("s_waitcnt vmcnt(" #N ")" ::: "memory");               \
        float4 wa = *(const float4*)&xbuf[wi][Q][4 * t];                    \
        float4 wb = *(const float4*)&xbuf[wi][Q][4 * t + 4];                \
        float4 wc = *(const float4*)&xbuf[wi][Q][4 * t + 8];                \
        asm volatile("s_waitcnt lgkmcnt(0)" ::: "memory");                  \
        FMAS(p##Q, wa, wb, wc);                                             \
    } while (0)

// Block = 9 waves = one output row (b,h). Wave wi: offset i=wi-4, x2 row
// r=h-i, PRIVATE 4-deep LDS ring of padded x2 rows (no cross-wave sharing,
// no main-loop barriers). x1 in a 4-slot register pipeline. Per wave-channel:
// 1 global_load_lds + 1 x1 quad load + 3 ds_read_b128 + 36 FMAs.
// Live set ~75 VGPR -- designed UNDER the backend's observed 84-reg cap
// (R4-R6: bigger live sets spill, attributes don't move the cap).
__global__ __launch_bounds__(576)
void corr_softmax_kernel(const float* __restrict__ x1,
                         const float* __restrict__ x2,
                         float* __restrict__ out)
{
    __shared__ float red[9][Wc];        // 9 KB softmax reduction
    __shared__ float xbuf[9][4][264];   // 38 KB private padded x2 rings

    const int tid = threadIdx.x;
    const int wi  = tid >> 6;   // 0..8
    const int t   = tid & 63;
    // XCD-aware swizzle (kept since R2: FETCH 294->~80 MB)
    const int bid = blockIdx.x;
    const int bh  = (bid & 7) * 128 + (bid >> 3);
    const int b   = bh >> 8;
    const int h   = bh & 255;

    float acc[9][4];
#pragma unroll
    for (int jj = 0; jj < 9; ++jj)
#pragma unroll
        for (int s = 0; s < 4; ++s)
            acc[jj][s] = 0.f;

    const int r = h + 4 - wi;  // x2 row = h - i
    if ((unsigned)r < (unsigned)Hc) {
        // zero the 4-float pads at both ends of each ring buffer
        if (t < 8) {
            const int idx = (t < 4) ? t : (256 + t);  // 0..3 / 260..263
#pragma unroll
            for (int q = 0; q < 4; ++q) xbuf[wi][q][idx] = 0.f;
        }
        asm volatile("s_waitcnt lgkmcnt(0)" ::: "memory");

        const float* x1p = x1 + (size_t)b * Cc * CH + (size_t)h * Wc + 4 * t;
        const float* x2p = x2 + (size_t)b * Cc * CH + (size_t)r * Wc + 4 * t;

        float4 p0, p1, p2, p3;
        // prologue: ordered (DMA, x1) pairs for channels 0..3
        GLOAD_LDS16(x2p + 0 * (size_t)CH, &xbuf[wi][0][4]);
        p0 = *(const float4*)(x1p + 0 * (size_t)CH);
        PIN();
        GLOAD_LDS16(x2p + 1 * (size_t)CH, &xbuf[wi][1][4]);
        p1 = *(const float4*)(x1p + 1 * (size_t)CH);
        PIN();
        GLOAD_LDS16(x2p + 2 * (size_t)CH, &xbuf[wi][2][4]);
        p2 = *(const float4*)(x1p + 2 * (size_t)CH);
        PIN();
        GLOAD_LDS16(x2p + 3 * (size_t)CH, &xbuf[wi][3][4]);
        p3 = *(const float4*)(x1p + 3 * (size_t)CH);
        PIN();

#pragma unroll 1
        for (int it = 0; it < 15; ++it) {   // channels 4it..4it+3, issue +4..+7
            PHASE(0);
            PHASE(1);
            PHASE(2);
            PHASE(3);
            x1p += 4 * (size_t)CH;
            x2p += 4 * (size_t)CH;
        }
        // tail: channels 60..63, drain the queue
        PHASE_T(0, 6);
        PHASE_T(1, 4);
        PHASE_T(2, 2);
        PHASE_T(3, 0);
    }

    // ---- softmax over 81 channels, reduced across the 9 waves ----
    float m0, m1, m2, m3;
    {
        float v0 = acc[0][0], v1 = acc[0][1], v2 = acc[0][2], v3 = acc[0][3];
#pragma unroll
        for (int jj = 1; jj < 9; ++jj) {
            v0 = fmaxf(v0, acc[jj][0]);
            v1 = fmaxf(v1, acc[jj][1]);
            v2 = fmaxf(v2, acc[jj][2]);
            v3 = fmaxf(v3, acc[jj][3]);
        }
        m0 = v0; m1 = v1; m2 = v2; m3 = v3;
    }
    *reinterpret_cast<float4*>(&red[wi][4 * t]) = make_float4(m0, m1, m2, m3);
    __syncthreads();

    float M0, M1, M2, M3;
    {
        float4 q = *reinterpret_cast<const float4*>(&red[0][4 * t]);
        M0 = q.x; M1 = q.y; M2 = q.z; M3 = q.w;
#pragma unroll
        for (int w2 = 1; w2 < 9; ++w2) {
            float4 qq = *reinterpret_cast<const float4*>(&red[w2][4 * t]);
            M0 = fmaxf(M0, qq.x); M1 = fmaxf(M1, qq.y);
            M2 = fmaxf(M2, qq.z); M3 = fmaxf(M3, qq.w);
        }
    }

    float s0 = 0.f, s1 = 0.f, s2 = 0.f, s3 = 0.f;
#pragma unroll
    for (int jj = 0; jj < 9; ++jj) {
        acc[jj][0] = __expf(acc[jj][0] - M0); s0 += acc[jj][0];
        acc[jj][1] = __expf(acc[jj][1] - M1); s1 += acc[jj][1];
        acc[jj][2] = __expf(acc[jj][2] - M2); s2 += acc[jj][2];
        acc[jj][3] = __expf(acc[jj][3] - M3); s3 += acc[jj][3];
    }
    __syncthreads();  // everyone done reading maxes
    *reinterpret_cast<float4*>(&red[wi][4 * t]) = make_float4(s0, s1, s2, s3);
    __syncthreads();

    float S0, S1, S2, S3;
    {
        float4 q = *reinterpret_cast<const float4*>(&red[0][4 * t]);
        S0 = q.x; S1 = q.y; S2 = q.z; S3 = q.w;
#pragma unroll
        for (int w2 = 1; w2 < 9; ++w2) {
            float4 qq = *reinterpret_cast<const float4*>(&red[w2][4 * t]);
            S0 += qq.x; S1 += qq.y; S2 += qq.z; S3 += qq.w;
        }
    }
    const float i0 = 1.0f / S0, i1 = 1.0f / S1, i2 = 1.0f / S2, i3 = 1.0f / S3;

    // k = (9*(wi-4) + (jj-4)) mod 81 = 9*wi + jj + 41 (mod 81)
    float* outp = out + (size_t)b * Dc * CH + (size_t)h * Wc + 4 * t;
#pragma unroll
    for (int jj = 0; jj < 9; ++jj) {
        int kc = 9 * wi + jj + 41;
        if (kc >= 81) kc -= 81;
        float4 o = make_float4(acc[jj][0] * i0, acc[jj][1] * i1,
                               acc[jj][2] * i2, acc[jj][3] * i3);
        *reinterpret_cast<float4*>(outp + (size_t)kc * CH) = o;
    }
}

extern "C" void kernel_launch(void* const* d_in, const int* in_sizes, int n_in,
                              void* d_out, int out_size, void* d_ws, size_t ws_size,
                              hipStream_t stream) {
    (void)in_sizes; (void)n_in; (void)d_ws; (void)ws_size; (void)out_size;
    const float* x1 = (const float*)d_in[0];
    const float* x2 = (const float*)d_in[1];
    float* out = (float*)d_out;
    dim3 grid(Bc * Hc);   // 1024 blocks: one per (b, h) row
    dim3 block(576);      // 9 waves
    hipLaunchKernelGGL(corr_softmax_kernel, grid, block, 0, stream, x1, x2, out);
}